// Round 1
// baseline (558.967 us; speedup 1.0000x reference)
//
#include <hip/hip_runtime.h>
#include <math.h>

#define N_P 256
#define T_T 1024
#define P_AR 4
#define TP (T_T - P_AR)          // 1020
#define ALPHA_LD (T_T + P_AR)    // 1028
#define NPAIRS (N_P * (N_P - 1) / 2)  // 32640
#define MCHUNK 8

// --- block reduction: 256 threads = 4 waves of 64 ---
__device__ __forceinline__ float block_reduce_sum(float v, float* tmp) {
#pragma unroll
    for (int o = 32; o > 0; o >>= 1) v += __shfl_down(v, o, 64);
    int lane = threadIdx.x & 63;
    int w    = threadIdx.x >> 6;
    if (lane == 0) tmp[w] = v;
    __syncthreads();
    if (threadIdx.x == 0) v = tmp[0] + tmp[1] + tmp[2] + tmp[3];
    return v;
}

// --- kernel A: colsum[t] = sum_j alpha[j, P+t]; out[1] += N * sum(actual^2) ---
__global__ __launch_bounds__(256) void colsum_kernel(const float* __restrict__ alpha,
                                                     float* __restrict__ colsum,
                                                     float* __restrict__ out) {
    __shared__ float tmp[4];
    int t = blockIdx.x * 256 + threadIdx.x;
    float cs = 0.f, sq = 0.f;
    if (t < TP) {
        for (int j = 0; j < N_P; ++j) {
            float a = alpha[j * ALPHA_LD + P_AR + t];
            cs += a;
            sq += a * a;
        }
        colsum[t] = cs;
    }
    float tot = block_reduce_sum(sq, tmp);
    if (threadIdx.x == 0) atomicAdd(out + 1, (float)N_P * tot);
}

// --- kernel B: AR main. block n: summed[n,t] for all t; accumulate
//     N*summed^2 - 2*summed*colsum[t] into out[1]. ---
__global__ __launch_bounds__(256) void ar_kernel(const float* __restrict__ Phi,
                                                 const float* __restrict__ alpha,
                                                 const float* __restrict__ colsum,
                                                 float* __restrict__ out) {
    __shared__ float phi_s[4 * N_P];                 // phi_s[k*256+m], 4 KB
    __shared__ __align__(16) float a_s[MCHUNK * 1024];  // 32 KB
    __shared__ float tmp[4];

    const int n   = blockIdx.x;
    const int tid = threadIdx.x;

    for (int x = tid; x < 4 * N_P; x += 256)
        phi_s[x] = Phi[(x >> 8) * (N_P * N_P) + n * N_P + (x & 255)];

    float acc0 = 0.f, acc1 = 0.f, acc2 = 0.f, acc3 = 0.f;
    const int t0 = tid * 4;                // 4 consecutive t per thread; tid=255 masked

    for (int mc = 0; mc < N_P; mc += MCHUNK) {
        __syncthreads();   // phi_s ready (first iter) / a_s safe to overwrite
        // stage rows mc..mc+7, columns 0..1023 (covers t+k max = 1019+3 = 1022)
        for (int x = tid; x < MCHUNK * 256; x += 256) {
            int r = x >> 8, c = x & 255;
            ((float4*)a_s)[r * 256 + c] =
                *(const float4*)(alpha + (size_t)(mc + r) * ALPHA_LD + c * 4);
        }
        __syncthreads();
        if (t0 < TP) {
#pragma unroll
            for (int r = 0; r < MCHUNK; ++r) {
                const float4 av0 = ((const float4*)(a_s + r * 1024))[tid];
                const float4 av1 = ((const float4*)(a_s + r * 1024))[tid + 1];
                int m = mc + r;
                float p0 = phi_s[m];
                float p1 = phi_s[256 + m];
                float p2 = phi_s[512 + m];
                float p3 = phi_s[768 + m];
                acc0 += p0 * av0.x + p1 * av0.y + p2 * av0.z + p3 * av0.w;
                acc1 += p0 * av0.y + p1 * av0.z + p2 * av0.w + p3 * av1.x;
                acc2 += p0 * av0.z + p1 * av0.w + p2 * av1.x + p3 * av1.y;
                acc3 += p0 * av0.w + p1 * av1.x + p2 * av1.y + p3 * av1.z;
            }
        }
    }

    float local = 0.f;
    if (t0 < TP) {   // TP % 4 == 0, so all 4 t's of an active thread are valid
        float c0 = colsum[t0], c1 = colsum[t0 + 1], c2 = colsum[t0 + 2], c3 = colsum[t0 + 3];
        local = 256.f * (acc0 * acc0 + acc1 * acc1 + acc2 * acc2 + acc3 * acc3)
              - 2.f * (acc0 * c0 + acc1 * c1 + acc2 * c2 + acc3 * c3);
    }
    __syncthreads();
    float tot = block_reduce_sum(local, tmp);
    if (tid == 0) atomicAdd(out + 1, tot);
}

// --- kernel C: log-BTL over upper-triangular pairs ---
__device__ __forceinline__ float btl_term(float z, float w, float a, float b) {
    float m   = fmaxf(a, b);
    float lse = m + __logf(1.f + __expf(-fabsf(a - b)));
    return z * (a - lse) + w * (b - lse);
}

__global__ __launch_bounds__(256) void btl_kernel(const float* __restrict__ Z,
                                                  const float* __restrict__ W,
                                                  const float* __restrict__ alpha,
                                                  float* __restrict__ out) {
    __shared__ float tmp[4];
    const int tid = threadIdx.x;
    float acc = 0.f;

    for (int q = blockIdx.x; q < NPAIRS; q += gridDim.x) {
        // triu pair index -> (i, j): offset(i) = i*(511-i)/2
        int i = (int)((511.0 - sqrt((double)(261121 - 8 * q))) * 0.5);
        if (i < 0) i = 0;
        if (i > 254) i = 254;
        while (i < 254 && ((i + 1) * (511 - (i + 1))) / 2 <= q) ++i;
        while ((i * (511 - i)) / 2 > q) --i;
        int j = q - (i * (511 - i)) / 2 + i + 1;

        const size_t base = (size_t)(i * N_P + j) * T_T + tid * 4;
        const float4 z  = *(const float4*)(Z + base);
        const float4 w  = *(const float4*)(W + base);
        const float4 si = *(const float4*)(alpha + (size_t)i * ALPHA_LD + P_AR + tid * 4);
        const float4 sj = *(const float4*)(alpha + (size_t)j * ALPHA_LD + P_AR + tid * 4);

        acc += btl_term(z.x, w.x, si.x, sj.x);
        acc += btl_term(z.y, w.y, si.y, sj.y);
        acc += btl_term(z.z, w.z, si.z, sj.z);
        acc += btl_term(z.w, w.w, si.w, sj.w);
    }

    float tot = block_reduce_sum(acc, tmp);
    if (tid == 0) atomicAdd(out, tot);
}

extern "C" void kernel_launch(void* const* d_in, const int* in_sizes, int n_in,
                              void* d_out, int out_size, void* d_ws, size_t ws_size,
                              hipStream_t stream) {
    const float* Z     = (const float*)d_in[0];
    const float* W     = (const float*)d_in[1];
    const float* Phi   = (const float*)d_in[2];
    const float* alpha = (const float*)d_in[3];
    float* out    = (float*)d_out;
    float* colsum = (float*)d_ws;   // TP floats

    hipMemsetAsync(d_out, 0, 2 * sizeof(float), stream);
    hipLaunchKernelGGL(colsum_kernel, dim3(4),    dim3(256), 0, stream, alpha, colsum, out);
    hipLaunchKernelGGL(ar_kernel,     dim3(N_P),  dim3(256), 0, stream, Phi, alpha, colsum, out);
    hipLaunchKernelGGL(btl_kernel,    dim3(2040), dim3(256), 0, stream, Z, W, alpha, out);
}

// Round 2
// 499.845 us; speedup vs baseline: 1.1183x; 1.1183x over previous
//
#include <hip/hip_runtime.h>
#include <math.h>

#define N_P 256
#define T_T 1024
#define P_AR 4
#define TP (T_T - P_AR)          // 1020
#define ALPHA_LD (T_T + P_AR)    // 1028
#define NPAIRS (N_P * (N_P - 1) / 2)  // 32640
#define MCHUNK 8
#define AR_BLOCKS 256
#define BTL_BLOCKS 2040

// --- block reduction: 256 threads = 4 waves of 64 ---
__device__ __forceinline__ float block_reduce_sum(float v, float* tmp) {
#pragma unroll
    for (int o = 32; o > 0; o >>= 1) v += __shfl_down(v, o, 64);
    int lane = threadIdx.x & 63;
    int w    = threadIdx.x >> 6;
    if (lane == 0) tmp[w] = v;
    __syncthreads();
    if (threadIdx.x == 0) v = tmp[0] + tmp[1] + tmp[2] + tmp[3];
    return v;
}

__device__ __forceinline__ float btl_term(float z, float w, float a, float b) {
    float m   = fmaxf(a, b);
    float lse = m + __logf(1.f + __expf(-fabsf(a - b)));
    return z * (a - lse) + w * (b - lse);
}

// Fused kernel: blocks [0,256) do the AR-error path (incl. in-loop column sums),
// blocks [256, 2296) do the log-BTL pair streaming. One kernel so the
// LDS/VALU-bound AR work co-schedules with HBM-bound BTL streaming.
__global__ __launch_bounds__(256) void fused_kernel(const float* __restrict__ Z,
                                                    const float* __restrict__ W,
                                                    const float* __restrict__ Phi,
                                                    const float* __restrict__ alpha,
                                                    float* __restrict__ out) {
    __shared__ float phi_s[4 * N_P];                    // 4 KB
    __shared__ __align__(16) float a_s[MCHUNK * 1024];  // 32 KB
    __shared__ float tmp[4];

    const int tid = threadIdx.x;

    if (blockIdx.x < AR_BLOCKS) {
        // ---------------- AR path: block n computes summed[n, :] ----------------
        const int n = blockIdx.x;

        for (int x = tid; x < 4 * N_P; x += 256)
            phi_s[x] = Phi[(x >> 8) * (N_P * N_P) + n * N_P + (x & 255)];

        float acc0 = 0.f, acc1 = 0.f, acc2 = 0.f, acc3 = 0.f;   // summed[n, t0..t0+3]
        float cs0 = 0.f, cs1 = 0.f, cs2 = 0.f, cs3 = 0.f;       // colsum[t0..t0+3]
        float sq  = 0.f;                                         // sum(actual^2)
        const int t0 = tid * 4;      // tid 255 masked (t0 >= TP)

        for (int mc = 0; mc < N_P; mc += MCHUNK) {
            __syncthreads();   // phi_s ready (first iter) / a_s reusable
            for (int x = tid; x < MCHUNK * 256; x += 256) {
                int r = x >> 8, c = x & 255;
                ((float4*)a_s)[r * 256 + c] =
                    *(const float4*)(alpha + (size_t)(mc + r) * ALPHA_LD + c * 4);
            }
            __syncthreads();
            if (t0 < TP) {
#pragma unroll
                for (int r = 0; r < MCHUNK; ++r) {
                    const float4 av0 = ((const float4*)(a_s + r * 1024))[tid];
                    const float4 av1 = ((const float4*)(a_s + r * 1024))[tid + 1];
                    int m = mc + r;
                    float p0 = phi_s[m];
                    float p1 = phi_s[256 + m];
                    float p2 = phi_s[512 + m];
                    float p3 = phi_s[768 + m];
                    acc0 += p0 * av0.x + p1 * av0.y + p2 * av0.z + p3 * av0.w;
                    acc1 += p0 * av0.y + p1 * av0.z + p2 * av0.w + p3 * av1.x;
                    acc2 += p0 * av0.z + p1 * av0.w + p2 * av1.x + p3 * av1.y;
                    acc3 += p0 * av0.w + p1 * av1.x + p2 * av1.y + p3 * av1.z;
                    // av1 == actual[m, t0..t0+3] — column sums + squares for free
                    cs0 += av1.x; cs1 += av1.y; cs2 += av1.z; cs3 += av1.w;
                    sq  += av1.x * av1.x + av1.y * av1.y + av1.z * av1.z + av1.w * av1.w;
                }
            }
        }

        float local = 0.f;
        if (t0 < TP) {
            local = 256.f * (acc0 * acc0 + acc1 * acc1 + acc2 * acc2 + acc3 * acc3)
                  - 2.f * (acc0 * cs0 + acc1 * cs1 + acc2 * cs2 + acc3 * cs3);
            if (n == 0) local += 256.f * sq;   // N * sum(actual^2), added once
        }
        __syncthreads();
        float tot = block_reduce_sum(local, tmp);
        if (tid == 0) atomicAdd(out + 1, tot);
    } else {
        // ---------------- BTL path: stream upper-triangular Z/W pairs ----------------
        float acc = 0.f;
        for (int q = blockIdx.x - AR_BLOCKS; q < NPAIRS; q += BTL_BLOCKS) {
            // triu pair index -> (i, j): offset(i) = i*(511-i)/2
            int i = (int)((511.0 - sqrt((double)(261121 - 8 * q))) * 0.5);
            if (i < 0) i = 0;
            if (i > 254) i = 254;
            while (i < 254 && ((i + 1) * (511 - (i + 1))) / 2 <= q) ++i;
            while ((i * (511 - i)) / 2 > q) --i;
            int j = q - (i * (511 - i)) / 2 + i + 1;

            const size_t base = (size_t)(i * N_P + j) * T_T + tid * 4;
            const float4 z  = *(const float4*)(Z + base);
            const float4 w  = *(const float4*)(W + base);
            const float4 si = *(const float4*)(alpha + (size_t)i * ALPHA_LD + P_AR + tid * 4);
            const float4 sj = *(const float4*)(alpha + (size_t)j * ALPHA_LD + P_AR + tid * 4);

            acc += btl_term(z.x, w.x, si.x, sj.x);
            acc += btl_term(z.y, w.y, si.y, sj.y);
            acc += btl_term(z.z, w.z, si.z, sj.z);
            acc += btl_term(z.w, w.w, si.w, sj.w);
        }
        float tot = block_reduce_sum(acc, tmp);
        if (tid == 0) atomicAdd(out, tot);
    }
}

extern "C" void kernel_launch(void* const* d_in, const int* in_sizes, int n_in,
                              void* d_out, int out_size, void* d_ws, size_t ws_size,
                              hipStream_t stream) {
    const float* Z     = (const float*)d_in[0];
    const float* W     = (const float*)d_in[1];
    const float* Phi   = (const float*)d_in[2];
    const float* alpha = (const float*)d_in[3];
    float* out = (float*)d_out;

    hipMemsetAsync(d_out, 0, 2 * sizeof(float), stream);
    hipLaunchKernelGGL(fused_kernel, dim3(AR_BLOCKS + BTL_BLOCKS), dim3(256), 0, stream,
                       Z, W, Phi, alpha, out);
}